// Round 1
// baseline (1016.328 us; speedup 1.0000x reference)
//
#include <hip/hip_runtime.h>

// CentroidPool: argmin_k ||x_i - c_k||^2 for N=131072 rows, K=1024 centroids, D=128.
// x^2 is row-constant -> argmin over 0.5*||c_k||^2 - x.c_k (exactly same argmin).
// Compute-bound on fp32 VALU (no fp32 MFMA on CDNA4): 1.72e10 FMA -> ~220us floor.

constexpr int N = 131072;
constexpr int K = 1024;
constexpr int D = 128;
constexpr int CT = 4; // centroids per inner tile (4 independent FMA chains)

// Precompute 0.5*||c_k||^2 into d_ws (4 KB).
__global__ void centroid_c2_kernel(const float* __restrict__ coords,
                                   float* __restrict__ c2half) {
    int k = blockIdx.x * 256 + threadIdx.x;
    if (k >= K) return;
    const float4* row = reinterpret_cast<const float4*>(coords + k * D);
    float s = 0.f;
#pragma unroll
    for (int i = 0; i < D / 4; ++i) {
        float4 v = row[i];
        s += v.x * v.x + v.y * v.y + v.z * v.z + v.w * v.w;
    }
    c2half[k] = 0.5f * s;
}

// One thread per latent row. Row held negated in 128 VGPRs; coords reads are
// wave-uniform -> compiler scalarizes to s_load feeding v_fmac_f32 (SGPR src).
__global__ __launch_bounds__(256) void centroid_argmin_kernel(
    const float* __restrict__ latent, const float* __restrict__ coords,
    const float* __restrict__ c2half, int* __restrict__ out) {
    int row = blockIdx.x * 256 + threadIdx.x;
    if (row >= N) return;

    float xn[D];
    const float4* rp = reinterpret_cast<const float4*>(latent + (size_t)row * D);
#pragma unroll
    for (int i = 0; i < D / 4; ++i) {
        float4 v = rp[i];
        xn[4 * i + 0] = -v.x;
        xn[4 * i + 1] = -v.y;
        xn[4 * i + 2] = -v.z;
        xn[4 * i + 3] = -v.w;
    }

    float best = 3.4e38f;
    int bestIdx = 0;
    for (int k0 = 0; k0 < K; k0 += CT) {
        float acc[CT];
#pragma unroll
        for (int c = 0; c < CT; ++c) acc[c] = c2half[k0 + c];
#pragma unroll
        for (int d = 0; d < D; ++d) {
#pragma unroll
            for (int c = 0; c < CT; ++c) {
                acc[c] = fmaf(xn[d], coords[(k0 + c) * D + d], acc[c]);
            }
        }
        // ascending k + strict '<' == numpy argmin first-occurrence tie-break
#pragma unroll
        for (int c = 0; c < CT; ++c) {
            if (acc[c] < best) { best = acc[c]; bestIdx = k0 + c; }
        }
    }
    out[row] = bestIdx;
}

extern "C" void kernel_launch(void* const* d_in, const int* in_sizes, int n_in,
                              void* d_out, int out_size, void* d_ws, size_t ws_size,
                              hipStream_t stream) {
    const float* latent = (const float*)d_in[0];
    const float* coords = (const float*)d_in[1];
    int* out = (int*)d_out;
    float* c2half = (float*)d_ws; // 4 KB scratch

    centroid_c2_kernel<<<(K + 255) / 256, 256, 0, stream>>>(coords, c2half);
    centroid_argmin_kernel<<<N / 256, 256, 0, stream>>>(latent, coords, c2half, out);
}

// Round 2
// 678.988 us; speedup vs baseline: 1.4968x; 1.4968x over previous
//
#include <hip/hip_runtime.h>

// CentroidPool: argmin_k ||x_i - c_k||^2, N=131072, K=1024, D=128, fp32.
// argmin over 0.5*||c_k||^2 - x.c_k (same argmin; x^2 row-constant).
// Structure: 1 thread = 1 row, row negated in VGPRs (pinned via asm);
// coords accesses wave-uniform -> compiler scalarizes to s_load + v_fmac(s).
// K-split x4 across blocks for occupancy; partial argmin combined in pass 2.

constexpr int N = 131072;
constexpr int K = 1024;
constexpr int D = 128;
constexpr int CT = 8; // centroids per inner tile (8 independent FMA chains)

// Precompute 0.5*||c_k||^2 (4 KB) into ws.
__global__ void centroid_c2_kernel(const float* __restrict__ coords,
                                   float* __restrict__ c2half) {
    int k = blockIdx.x * 256 + threadIdx.x;
    if (k >= K) return;
    const float4* row = reinterpret_cast<const float4*>(coords + k * D);
    float s = 0.f;
#pragma unroll
    for (int i = 0; i < D / 4; ++i) {
        float4 v = row[i];
        s += v.x * v.x + v.y * v.y + v.z * v.z + v.w * v.w;
    }
    c2half[k] = 0.5f * s;
}

template <int KSPL>
__global__ __launch_bounds__(256, 2) void centroid_partial_kernel(
    const float* __restrict__ latent, const float* __restrict__ coords,
    const float* __restrict__ c2half, float* __restrict__ pval,
    int* __restrict__ pidx, int* __restrict__ out) {
    const int row = blockIdx.x * 256 + threadIdx.x;
    const int kbase = blockIdx.y * (K / KSPL);

    // Negated latent row, pinned in VGPRs (asm blocks rematerialization).
    float xn[D];
    const float4* rp = reinterpret_cast<const float4*>(latent + (size_t)row * D);
#pragma unroll
    for (int i = 0; i < D / 4; ++i) {
        float4 v = rp[i];
        xn[4 * i + 0] = -v.x;
        xn[4 * i + 1] = -v.y;
        xn[4 * i + 2] = -v.z;
        xn[4 * i + 3] = -v.w;
    }
#pragma unroll
    for (int i = 0; i < D; ++i) asm volatile("" : "+v"(xn[i]));

    float best = 3.4e38f;
    int bi = kbase;
    for (int k0 = kbase; k0 < kbase + K / KSPL; k0 += CT) {
        float acc[CT];
#pragma unroll
        for (int c = 0; c < CT; ++c) acc[c] = c2half[k0 + c];
#pragma unroll
        for (int d = 0; d < D; ++d) {
#pragma unroll
            for (int c = 0; c < CT; ++c)
                acc[c] = fmaf(xn[d], coords[(k0 + c) * D + d], acc[c]);
        }
        // ascending k + strict '<' == numpy first-occurrence tie-break
#pragma unroll
        for (int c = 0; c < CT; ++c)
            if (acc[c] < best) { best = acc[c]; bi = k0 + c; }
    }
    if (KSPL == 1) {
        out[row] = bi;
    } else {
        pval[blockIdx.y * N + row] = best;
        pidx[blockIdx.y * N + row] = bi;
    }
}

__global__ void centroid_combine_kernel(const float* __restrict__ pval,
                                        const int* __restrict__ pidx,
                                        int* __restrict__ out, int nspl) {
    int row = blockIdx.x * 256 + threadIdx.x;
    float best = pval[row];
    int bi = pidx[row];
    for (int s = 1; s < nspl; ++s) {
        // lower split always has lower k, so strict '<' keeps first occurrence
        float v = pval[s * N + row];
        if (v < best) { best = v; bi = pidx[s * N + row]; }
    }
    out[row] = bi;
}

extern "C" void kernel_launch(void* const* d_in, const int* in_sizes, int n_in,
                              void* d_out, int out_size, void* d_ws, size_t ws_size,
                              hipStream_t stream) {
    const float* latent = (const float*)d_in[0];
    const float* coords = (const float*)d_in[1];
    int* out = (int*)d_out;

    constexpr int KSPL = 4;
    char* ws = (char*)d_ws;
    float* c2half = (float*)ws;                       // 4 KB
    float* pval = (float*)(ws + 4096);                // KSPL*N*4 = 2 MB
    int* pidx = (int*)(ws + 4096 + KSPL * N * 4);     // KSPL*N*4 = 2 MB
    const size_t need = 4096 + (size_t)KSPL * N * 8;

    centroid_c2_kernel<<<(K + 255) / 256, 256, 0, stream>>>(coords, c2half);

    if (ws_size >= need) {
        dim3 grid(N / 256, KSPL);
        centroid_partial_kernel<KSPL><<<grid, 256, 0, stream>>>(
            latent, coords, c2half, pval, pidx, out);
        centroid_combine_kernel<<<N / 256, 256, 0, stream>>>(pval, pidx, out, KSPL);
    } else {
        dim3 grid(N / 256, 1);
        centroid_partial_kernel<1><<<grid, 256, 0, stream>>>(
            latent, coords, c2half, nullptr, nullptr, out);
    }
}

// Round 3
// 674.147 us; speedup vs baseline: 1.5076x; 1.0072x over previous
//
#include <hip/hip_runtime.h>

// CentroidPool: argmin_k ||x_i - c_k||^2, N=131072, K=1024, D=128, fp32.
// argmin over 0.5*||c_k||^2 - x.c_k (same argmin; x^2 row-constant).
// One thread = one row. Latent row negated and PINNED in VGPRs (asm pins
// INSIDE the k-loop -> loop-carried liveness, compiler cannot rematerialize
// the global loads). coords accesses are wave-uniform -> scalarized s_load
// feeding v_fmac_f32 with SGPR operand. K-split x4 for grid parallelism.

constexpr int N = 131072;
constexpr int K = 1024;
constexpr int D = 128;
constexpr int CT = 8; // centroids per inner tile (8 independent FMA chains)

// Precompute 0.5*||c_k||^2 (4 KB) into ws.
__global__ void centroid_c2_kernel(const float* __restrict__ coords,
                                   float* __restrict__ c2half) {
    int k = blockIdx.x * 256 + threadIdx.x;
    if (k >= K) return;
    const float4* row = reinterpret_cast<const float4*>(coords + k * D);
    float s = 0.f;
#pragma unroll
    for (int i = 0; i < D / 4; ++i) {
        float4 v = row[i];
        s += v.x * v.x + v.y * v.y + v.z * v.z + v.w * v.w;
    }
    c2half[k] = 0.5f * s;
}

template <int KSPL>
__global__ __launch_bounds__(256, 2) void centroid_partial_kernel(
    const float* __restrict__ latent, const float* __restrict__ coords,
    const float* __restrict__ c2half, float* __restrict__ pval,
    int* __restrict__ pidx, int* __restrict__ out) {
    const int row = blockIdx.x * 256 + threadIdx.x;
    const int kbase = blockIdx.y * (K / KSPL);

    // Negated latent row -> VGPRs.
    float xn[D];
    const float4* rp = reinterpret_cast<const float4*>(latent + (size_t)row * D);
#pragma unroll
    for (int i = 0; i < D / 4; ++i) {
        float4 v = rp[i];
        xn[4 * i + 0] = -v.x;
        xn[4 * i + 1] = -v.y;
        xn[4 * i + 2] = -v.z;
        xn[4 * i + 3] = -v.w;
    }

    float best = 3.4e38f;
    int bi = kbase;
    for (int k0 = kbase; k0 < kbase + K / KSPL; k0 += CT) {
        // Pin the row in VGPRs EVERY iteration: loop-carried asm use forces
        // all 128 values live in registers across the loop (no remat/reload).
#pragma unroll
        for (int i = 0; i < D; ++i) asm volatile("" : "+v"(xn[i]));

        float acc[CT];
#pragma unroll
        for (int c = 0; c < CT; ++c) acc[c] = c2half[k0 + c];
#pragma unroll
        for (int d = 0; d < D; ++d) {
#pragma unroll
            for (int c = 0; c < CT; ++c)
                acc[c] = fmaf(xn[d], coords[(k0 + c) * D + d], acc[c]);
        }
        // ascending k + strict '<' == numpy first-occurrence tie-break
#pragma unroll
        for (int c = 0; c < CT; ++c)
            if (acc[c] < best) { best = acc[c]; bi = k0 + c; }
    }
    if (KSPL == 1) {
        out[row] = bi;
    } else {
        pval[blockIdx.y * N + row] = best;
        pidx[blockIdx.y * N + row] = bi;
    }
}

__global__ void centroid_combine_kernel(const float* __restrict__ pval,
                                        const int* __restrict__ pidx,
                                        int* __restrict__ out, int nspl) {
    int row = blockIdx.x * 256 + threadIdx.x;
    float best = pval[row];
    int bi = pidx[row];
    for (int s = 1; s < nspl; ++s) {
        // lower split always has lower k, so strict '<' keeps first occurrence
        float v = pval[s * N + row];
        if (v < best) { best = v; bi = pidx[s * N + row]; }
    }
    out[row] = bi;
}

extern "C" void kernel_launch(void* const* d_in, const int* in_sizes, int n_in,
                              void* d_out, int out_size, void* d_ws, size_t ws_size,
                              hipStream_t stream) {
    const float* latent = (const float*)d_in[0];
    const float* coords = (const float*)d_in[1];
    int* out = (int*)d_out;

    constexpr int KSPL = 4;
    char* ws = (char*)d_ws;
    float* c2half = (float*)ws;                       // 4 KB
    float* pval = (float*)(ws + 4096);                // KSPL*N*4 = 2 MB
    int* pidx = (int*)(ws + 4096 + KSPL * N * 4);     // KSPL*N*4 = 2 MB
    const size_t need = 4096 + (size_t)KSPL * N * 8;

    centroid_c2_kernel<<<(K + 255) / 256, 256, 0, stream>>>(coords, c2half);

    if (ws_size >= need) {
        dim3 grid(N / 256, KSPL);
        centroid_partial_kernel<KSPL><<<grid, 256, 0, stream>>>(
            latent, coords, c2half, pval, pidx, out);
        centroid_combine_kernel<<<N / 256, 256, 0, stream>>>(pval, pidx, out, KSPL);
    } else {
        dim3 grid(N / 256, 1);
        centroid_partial_kernel<1><<<grid, 256, 0, stream>>>(
            latent, coords, c2half, nullptr, nullptr, out);
    }
}